// Round 12
// baseline (205.763 us; speedup 1.0000x reference)
//
#include <hip/hip_runtime.h>
#include <math.h>

#define NN 100000   // nodes
#define NE 600000   // edges
#define DD 128      // hidden dim
#define NB_SCAN 98  // ceil(NN/1024)

// k_setup grid sections
#define NB_CAST 12500   // NN*32 float4s / 256
#define NB_PREPW 64     // 128*128 / 256
#define NB_PREPW2 8     // 16*128 / 256
#define NB_DEG 2344     // ceil(NE/256)

typedef __attribute__((ext_vector_type(8))) short bf16x8;
typedef __attribute__((ext_vector_type(4))) float f32x4;
typedef __attribute__((ext_vector_type(4))) unsigned int u32x4;  // clang vector for NT stores
typedef unsigned short u16;
typedef unsigned int u32;

__device__ __forceinline__ float bflo(u32 w) {
    union { u32 i; float f; } v; v.i = w << 16; return v.f;
}
__device__ __forceinline__ float bfhi(u32 w) {
    union { u32 i; float f; } v; v.i = w & 0xffff0000u; return v.f;
}
__device__ __forceinline__ u16 f2bf(float f) {
    union { float f; u32 u; } v; v.f = f;
    u32 r = v.u + 0x7fffu + ((v.u >> 16) & 1u);  // RNE
    return (u16)(r >> 16);
}

// ---------------- setup: cast + weight prep + degree + zero-rows ----------

__global__ __launch_bounds__(256) void k_setup(const float* __restrict__ x,
                                               u16* __restrict__ xb,
                                               const float* __restrict__ Wl0,
                                               const float* __restrict__ Wr0,
                                               const float* __restrict__ Wl1,
                                               const float* __restrict__ Wr1,
                                               const float* __restrict__ Wl2,
                                               const float* __restrict__ Wr2,
                                               u16* __restrict__ Wc0,
                                               u16* __restrict__ Wc1,
                                               u16* __restrict__ Wc2,
                                               const int* __restrict__ dst,
                                               int* __restrict__ deg,
                                               u16* __restrict__ H1,
                                               u16* __restrict__ hl2b) {
    int b = blockIdx.x;
    int tid = threadIdx.x;
    if (b < NB_CAST) {
        int i = b * 256 + tid;               // float4 index, exact
        float4 v = reinterpret_cast<const float4*>(x)[i];
        ushort4 o;
        o.x = f2bf(v.x); o.y = f2bf(v.y); o.z = f2bf(v.z); o.w = f2bf(v.w);
        reinterpret_cast<ushort4*>(xb)[i] = o;
    } else if (b < NB_CAST + NB_PREPW) {
        int t = (b - NB_CAST) * 256 + tid;   // 0..16383, exact
        int j = t >> 7, k = t & 127;
        Wc0[j * 256 + k]       = f2bf(Wl0[t]);
        Wc0[j * 256 + 128 + k] = f2bf(Wr0[t]);
        Wc1[j * 256 + k]       = f2bf(Wl1[t]);
        Wc1[j * 256 + 128 + k] = f2bf(Wr1[t]);
    } else if (b < NB_CAST + NB_PREPW + NB_PREPW2) {
        int t = (b - NB_CAST - NB_PREPW) * 256 + tid;  // 0..2047
        int j = t >> 7, k = t & 127;
        Wc2[j * 128 + k]        = f2bf(Wl2[t]);
        Wc2[(16 + j) * 128 + k] = f2bf(Wr2[t]);
    } else if (b < NB_CAST + NB_PREPW + NB_PREPW2 + NB_DEG) {
        int e = (b - NB_CAST - NB_PREPW - NB_PREPW2) * 256 + tid;
        if (e < NE) atomicAdd(&deg[dst[e]], 1);
    } else {
        // zero rows at index NN (targets of padded edges)
        if (tid < DD) { xb[(size_t)NN * DD + tid] = 0; H1[(size_t)NN * DD + tid] = 0; }
        if (tid < 16) hl2b[(size_t)NN * 16 + tid] = 0;
    }
}

// ---------------- CSR build (padded to multiples of 4) ----------------
// scan1: per-block padded-degree sums + iteration-count histogram; the LAST
// block (done-counter) also performs the former scan2 work: exclusive scan
// of block sums (in-place in bsum) + DESCENDING bucket cursor build.

__global__ __launch_bounds__(256) void k_scan1(const int* __restrict__ deg,
                                               int* __restrict__ bsum,
                                               int* __restrict__ hist,
                                               int* __restrict__ done,
                                               int* __restrict__ cursor) {
    __shared__ int sm[256];
    __shared__ int lh[32];
    __shared__ int isLast;
    int t = threadIdx.x;
    if (t < 32) lh[t] = 0;
    int idx = blockIdx.x * 1024 + t * 4;
    int4 v = make_int4(0, 0, 0, 0);
    if (idx + 3 < NN) v = *reinterpret_cast<const int4*>(deg + idx);
    else {
        if (idx     < NN) v.x = deg[idx];
        if (idx + 1 < NN) v.y = deg[idx + 1];
        if (idx + 2 < NN) v.z = deg[idx + 2];
        if (idx + 3 < NN) v.w = deg[idx + 3];
    }
    int p0 = (v.x + 3) & ~3, p1 = (v.y + 3) & ~3, p2 = (v.z + 3) & ~3, p3 = (v.w + 3) & ~3;
    sm[t] = p0 + p1 + p2 + p3;
    __syncthreads();
    if (idx     < NN) atomicAdd(&lh[min(p0 >> 2, 31)], 1);
    if (idx + 1 < NN) atomicAdd(&lh[min(p1 >> 2, 31)], 1);
    if (idx + 2 < NN) atomicAdd(&lh[min(p2 >> 2, 31)], 1);
    if (idx + 3 < NN) atomicAdd(&lh[min(p3 >> 2, 31)], 1);
    __syncthreads();
    if (t < 32) atomicAdd(&hist[t], lh[t]);
    for (int off = 128; off > 0; off >>= 1) {
        if (t < off) sm[t] += sm[t + off];
        __syncthreads();
    }
    if (t == 0) bsum[blockIdx.x] = sm[0];

    // last-block-done: perform global scan of bsum + cursor build
    __threadfence();
    if (t == 0) isLast = (atomicAdd(done, 1) == NB_SCAN - 1);
    __syncthreads();
    if (!isLast) return;
    int bv = (t < NB_SCAN) ? bsum[t] : 0;
    sm[t] = bv;
    __syncthreads();
    for (int off = 1; off < 256; off <<= 1) {
        int add = (t >= off) ? sm[t - off] : 0;
        __syncthreads();
        sm[t] += add;
        __syncthreads();
    }
    if (t < NB_SCAN) bsum[t] = (t == 0) ? 0 : sm[t - 1];  // exclusive, in-place
    if (t == 0) {   // DESCENDING bucket order: heavy blocks dispatched first
        int r = 0;
        for (int c = 31; c >= 0; --c) { cursor[c] = r; r += hist[c]; }
    }
}

// scan3: padded CSR offsets + pad-fill + per-node descriptor (bucketed order)
__global__ __launch_bounds__(256) void k_scan3(const int* __restrict__ deg,
                                               const int* __restrict__ boff,
                                               int* __restrict__ cur,
                                               int* __restrict__ col2,
                                               int* __restrict__ cursor,
                                               int4* __restrict__ desc) {
    __shared__ int sm[256];
    __shared__ int lh[32];
    __shared__ int lb[32];
    int t = threadIdx.x;
    if (t < 32) lh[t] = 0;
    int idx = blockIdx.x * 1024 + t * 4;
    int4 v = make_int4(0, 0, 0, 0);
    if (idx + 3 < NN) v = *reinterpret_cast<const int4*>(deg + idx);
    else {
        if (idx     < NN) v.x = deg[idx];
        if (idx + 1 < NN) v.y = deg[idx + 1];
        if (idx + 2 < NN) v.z = deg[idx + 2];
        if (idx + 3 < NN) v.w = deg[idx + 3];
    }
    int p0 = (v.x + 3) & ~3, p1 = (v.y + 3) & ~3, p2 = (v.z + 3) & ~3, p3 = (v.w + 3) & ~3;
    sm[t] = p0 + p1 + p2 + p3;
    __syncthreads();
    for (int off = 1; off < 256; off <<= 1) {
        int add = (t >= off) ? sm[t - off] : 0;
        __syncthreads();
        sm[t] += add;
        __syncthreads();
    }
    int run = boff[blockIdx.x] + ((t == 0) ? 0 : sm[t - 1]);
    int d[4] = {v.x, v.y, v.z, v.w};
    int p[4] = {p0, p1, p2, p3};
    int begs[4], ci[4], myi[4];
#pragma unroll
    for (int i = 0; i < 4; ++i) {
        if (idx + i < NN) {
            begs[i] = run;
            cur[idx + i] = run;
            for (int q = run + d[i]; q < run + p[i]; ++q) col2[q] = NN;  // pads -> zero row
            ci[i] = min(p[i] >> 2, 31);
            myi[i] = atomicAdd(&lh[ci[i]], 1);
            run += p[i];
        }
    }
    __syncthreads();
    if (t < 32 && lh[t] > 0) lb[t] = atomicAdd(&cursor[t], lh[t]);
    __syncthreads();
#pragma unroll
    for (int i = 0; i < 4; ++i) {
        if (idx + i < NN) {
            float iv = 1.0f / (float)(d[i] > 0 ? d[i] : 1);
            desc[lb[ci[i]] + myi[i]] =
                make_int4(idx + i, begs[i], begs[i] + p[i], __float_as_int(iv));
        }
    }
}

// scatter: 2 edges per thread (vectorized index reads)
__global__ __launch_bounds__(256) void k_scatter(const int* __restrict__ src,
                                                 const int* __restrict__ dst,
                                                 int* __restrict__ cur,
                                                 int* __restrict__ col2) {
    int e = (blockIdx.x * 256 + threadIdx.x) * 2;
    if (e + 1 < NE) {
        int2 s = *reinterpret_cast<const int2*>(src + e);
        int2 d = *reinterpret_cast<const int2*>(dst + e);
        int q0 = atomicAdd(&cur[d.x], 1);
        col2[q0] = s.x;
        int q1 = atomicAdd(&cur[d.y], 1);
        col2[q1] = s.y;
    } else if (e < NE) {
        int q = atomicAdd(&cur[dst[e]], 1);
        col2[q] = src[e];
    }
}

// ---------------- fused SAGE layer (layers 0/1) ----------------
// One block = 32 nodes via desc (degree-bucketed, heavy-first), 8 lanes/node.
// Phase 1: mean-gather with col-index prefetch pipeline -> LDS [agg|x] K=256
// swizzled (rows 512B). Phase 2: 4 waves x {2 node-groups x 32 cols}: W-frag
// register reuse x2, 32 MFMAs. Epilogue -> LDS -> full-row NT stores (STORE)
// or fused W2 transform producing hl2b/hr2 (DOW2; H2 never hits HBM).

template<bool STORE, bool DOW2>
__global__ __launch_bounds__(256) void k_fused_layer(const u16* __restrict__ X,
                                                     const int* __restrict__ col2,
                                                     const int4* __restrict__ desc,
                                                     const u16* __restrict__ Wc,
                                                     const float* __restrict__ b,
                                                     u16* __restrict__ out,
                                                     const u16* __restrict__ Wc2,
                                                     u16* __restrict__ hl2b,
                                                     float* __restrict__ hr2) {
    __shared__ u16 XK[32 * 256];  // 16 KB; row = local node (512 B), swizzle: byte ^ (r&7)<<4
    char* lds = reinterpret_cast<char*>(XK);

    int tid = threadIdx.x;
    int nl = tid >> 3;     // local node 0..31
    int sl = tid & 7;      // 32B k-slice 0..7
    int4 d = desc[blockIdx.x * 32 + nl];
    int n = d.x, beg = d.y, end = d.z;
    float iv = __int_as_float(d.w);
    int m = (nl & 7) << 4;

    // first col quad as early as possible (starts the pointer chain)
    int4 c = make_int4(NN, NN, NN, NN);
    if (beg < end) c = *reinterpret_cast<const int4*>(col2 + beg);

    // self row -> LDS bytes [256 + sl*32, +32)
    {
        const u16* xs = X + (size_t)n * DD + sl * 16;
        uint4 s0 = *reinterpret_cast<const uint4*>(xs);
        uint4 s1 = *reinterpret_cast<const uint4*>(xs + 8);
        int boff = 256 + sl * 32;
        *reinterpret_cast<uint4*>(lds + nl * 512 + (boff ^ m)) = s0;
        *reinterpret_cast<uint4*>(lds + nl * 512 + ((boff + 16) ^ m)) = s1;
    }

    // mean-gather: padded list (multiple of 4), col prefetch pipeline
    float a0 = 0.f, a1 = 0.f, a2 = 0.f, a3 = 0.f, a4 = 0.f, a5 = 0.f, a6 = 0.f, a7 = 0.f;
    float a8 = 0.f, a9 = 0.f, a10 = 0.f, a11 = 0.f, a12 = 0.f, a13 = 0.f, a14 = 0.f, a15 = 0.f;
    for (int e = beg; e < end; e += 4) {
        int4 cn = make_int4(NN, NN, NN, NN);
        if (e + 4 < end) cn = *reinterpret_cast<const int4*>(col2 + e + 4);
        const u16* p0 = X + (size_t)c.x * DD + sl * 16;
        const u16* p1 = X + (size_t)c.y * DD + sl * 16;
        const u16* p2 = X + (size_t)c.z * DD + sl * 16;
        const u16* p3 = X + (size_t)c.w * DD + sl * 16;
        uint4 v0 = *reinterpret_cast<const uint4*>(p0);
        uint4 w0 = *reinterpret_cast<const uint4*>(p0 + 8);
        uint4 v1 = *reinterpret_cast<const uint4*>(p1);
        uint4 w1 = *reinterpret_cast<const uint4*>(p1 + 8);
        uint4 v2 = *reinterpret_cast<const uint4*>(p2);
        uint4 w2 = *reinterpret_cast<const uint4*>(p2 + 8);
        uint4 v3 = *reinterpret_cast<const uint4*>(p3);
        uint4 w3 = *reinterpret_cast<const uint4*>(p3 + 8);
        a0  += (bflo(v0.x) + bflo(v1.x)) + (bflo(v2.x) + bflo(v3.x));
        a1  += (bfhi(v0.x) + bfhi(v1.x)) + (bfhi(v2.x) + bfhi(v3.x));
        a2  += (bflo(v0.y) + bflo(v1.y)) + (bflo(v2.y) + bflo(v3.y));
        a3  += (bfhi(v0.y) + bfhi(v1.y)) + (bfhi(v2.y) + bfhi(v3.y));
        a4  += (bflo(v0.z) + bflo(v1.z)) + (bflo(v2.z) + bflo(v3.z));
        a5  += (bfhi(v0.z) + bfhi(v1.z)) + (bfhi(v2.z) + bfhi(v3.z));
        a6  += (bflo(v0.w) + bflo(v1.w)) + (bflo(v2.w) + bflo(v3.w));
        a7  += (bfhi(v0.w) + bfhi(v1.w)) + (bfhi(v2.w) + bfhi(v3.w));
        a8  += (bflo(w0.x) + bflo(w1.x)) + (bflo(w2.x) + bflo(w3.x));
        a9  += (bfhi(w0.x) + bfhi(w1.x)) + (bfhi(w2.x) + bfhi(w3.x));
        a10 += (bflo(w0.y) + bflo(w1.y)) + (bflo(w2.y) + bflo(w3.y));
        a11 += (bfhi(w0.y) + bfhi(w1.y)) + (bfhi(w2.y) + bfhi(w3.y));
        a12 += (bflo(w0.z) + bflo(w1.z)) + (bflo(w2.z) + bflo(w3.z));
        a13 += (bfhi(w0.z) + bfhi(w1.z)) + (bfhi(w2.z) + bfhi(w3.z));
        a14 += (bflo(w0.w) + bflo(w1.w)) + (bflo(w2.w) + bflo(w3.w));
        a15 += (bfhi(w0.w) + bfhi(w1.w)) + (bfhi(w2.w) + bfhi(w3.w));
        c = cn;
    }
    uint4 o0, o1;
    o0.x = (u32)f2bf(a0 * iv)  | ((u32)f2bf(a1 * iv)  << 16);
    o0.y = (u32)f2bf(a2 * iv)  | ((u32)f2bf(a3 * iv)  << 16);
    o0.z = (u32)f2bf(a4 * iv)  | ((u32)f2bf(a5 * iv)  << 16);
    o0.w = (u32)f2bf(a6 * iv)  | ((u32)f2bf(a7 * iv)  << 16);
    o1.x = (u32)f2bf(a8 * iv)  | ((u32)f2bf(a9 * iv)  << 16);
    o1.y = (u32)f2bf(a10 * iv) | ((u32)f2bf(a11 * iv) << 16);
    o1.z = (u32)f2bf(a12 * iv) | ((u32)f2bf(a13 * iv) << 16);
    o1.w = (u32)f2bf(a14 * iv) | ((u32)f2bf(a15 * iv) << 16);
    *reinterpret_cast<uint4*>(lds + nl * 512 + ((sl * 32) ^ m)) = o0;
    *reinterpret_cast<uint4*>(lds + nl * 512 + ((sl * 32 + 16) ^ m)) = o1;
    __syncthreads();

    // ---- phase 2: GEMM (W-frag reused across 2 node-groups) ----
    int wid = tid >> 6, lane = tid & 63;
    int cl = lane & 15, rq = lane >> 4;
    int xm = (cl & 7) << 4;

    f32x4 acc00 = (f32x4){0.f, 0.f, 0.f, 0.f};
    f32x4 acc01 = (f32x4){0.f, 0.f, 0.f, 0.f};
    f32x4 acc10 = (f32x4){0.f, 0.f, 0.f, 0.f};
    f32x4 acc11 = (f32x4){0.f, 0.f, 0.f, 0.f};
    const u16* wbase = Wc + (size_t)(wid * 32 + cl) * 256 + rq * 8;
    const char* x0b = lds + cl * 512;
    const char* x1b = lds + (16 + cl) * 512;
#pragma unroll
    for (int ks = 0; ks < 8; ++ks) {
        int xo = (ks * 64 + rq * 16) ^ xm;
        bf16x8 xf0 = *reinterpret_cast<const bf16x8*>(x0b + xo);
        bf16x8 xf1 = *reinterpret_cast<const bf16x8*>(x1b + xo);
        bf16x8 wf0 = *reinterpret_cast<const bf16x8*>(wbase + ks * 32);
        bf16x8 wf1 = *reinterpret_cast<const bf16x8*>(wbase + 16 * 256 + ks * 32);
        acc00 = __builtin_amdgcn_mfma_f32_16x16x32_bf16(wf0, xf0, acc00, 0, 0, 0);
        acc01 = __builtin_amdgcn_mfma_f32_16x16x32_bf16(wf1, xf0, acc01, 0, 0, 0);
        acc10 = __builtin_amdgcn_mfma_f32_16x16x32_bf16(wf0, xf1, acc10, 0, 0, 0);
        acc11 = __builtin_amdgcn_mfma_f32_16x16x32_bf16(wf1, xf1, acc11, 0, 0, 0);
    }
    __syncthreads();   // XK reads done; safe to overwrite with output tile

    // bias + relu + pack -> LDS (node-row g*16+cl, col bytes (j*2)^swz)
#pragma unroll
    for (int g = 0; g < 2; ++g) {
#pragma unroll
        for (int jf = 0; jf < 2; ++jf) {
            f32x4 a = g ? (jf ? acc11 : acc10) : (jf ? acc01 : acc00);
            int j0 = wid * 32 + jf * 16 + rq * 4;
            float4 bias = *reinterpret_cast<const float4*>(b + j0);
            float o0f = fmaxf(a[0] + bias.x, 0.f);
            float o1f = fmaxf(a[1] + bias.y, 0.f);
            float o2f = fmaxf(a[2] + bias.z, 0.f);
            float o3f = fmaxf(a[3] + bias.w, 0.f);
            uint2 pk;
            pk.x = (u32)f2bf(o0f) | ((u32)f2bf(o1f) << 16);
            pk.y = (u32)f2bf(o2f) | ((u32)f2bf(o3f) << 16);
            int row = g * 16 + cl;
            *reinterpret_cast<uint2*>(lds + row * 512 + ((j0 * 2) ^ ((cl & 7) << 4))) = pk;
        }
    }
    __syncthreads();

    if (STORE) {
        // full-row NT stores (don't evict the gather table from L2):
        // thread (nl, sl) stores bytes [sl*32, +32) of row n
        u32x4 q0 = *reinterpret_cast<const u32x4*>(lds + nl * 512 + ((sl * 32) ^ m));
        u32x4 q1 = *reinterpret_cast<const u32x4*>(lds + nl * 512 + ((sl * 32 + 16) ^ m));
        u32x4* orow = reinterpret_cast<u32x4*>(out + (size_t)n * DD + sl * 16);
        __builtin_nontemporal_store(q0, orow);
        __builtin_nontemporal_store(q1, orow + 1);
    }

    if (DOW2) {
        // fused layer-2 transforms from the LDS output tile (K=128)
        int g = wid >> 1, tbl = wid & 1;
        f32x4 a2 = (f32x4){0.f, 0.f, 0.f, 0.f};
        const u16* wb = Wc2 + (size_t)(tbl * 16 + cl) * 128 + rq * 8;
        const char* xb = lds + (size_t)(g * 16 + cl) * 512;
#pragma unroll
        for (int ks = 0; ks < 4; ++ks) {
            bf16x8 xf = *reinterpret_cast<const bf16x8*>(xb + ((ks * 64 + rq * 16) ^ xm));
            bf16x8 wf = *reinterpret_cast<const bf16x8*>(wb + ks * 32);
            a2 = __builtin_amdgcn_mfma_f32_16x16x32_bf16(wf, xf, a2, 0, 0, 0);
        }
        int n2 = desc[blockIdx.x * 32 + g * 16 + cl].x;
        if (tbl == 0) {
            uint2 pk;
            pk.x = (u32)f2bf(a2[0]) | ((u32)f2bf(a2[1]) << 16);
            pk.y = (u32)f2bf(a2[2]) | ((u32)f2bf(a2[3]) << 16);
            *reinterpret_cast<uint2*>(hl2b + (size_t)n2 * 16 + rq * 4) = pk;
        } else {
            *reinterpret_cast<float4*>(hr2 + (size_t)n2 * 16 + rq * 4) =
                make_float4(a2[0], a2[1], a2[2], a2[3]);
        }
    }
}

// ---------------- layer 2 final ----------------

// k_l2_final: 8 lanes/node mean-gather(hl2b) + hr2 + bias -> log_softmax.
__global__ __launch_bounds__(256) void k_l2_final(const u16* __restrict__ hl2b,
                                                  const float* __restrict__ hr2,
                                                  const int* __restrict__ col2,
                                                  const int4* __restrict__ desc,
                                                  const float* __restrict__ b2,
                                                  float* __restrict__ out) {
    int tid = threadIdx.x;
    int ns = tid >> 3;   // node slot 0..31
    int l  = tid & 7;
    int4 d = desc[blockIdx.x * 32 + ns];
    int n = d.x, beg = d.y, end = d.z;
    float iv = __int_as_float(d.w);

    float ag[16];
#pragma unroll
    for (int j = 0; j < 16; ++j) ag[j] = 0.f;
    for (int e = beg + l; e < end; e += 8) {
        const u16* r = hl2b + (size_t)col2[e] * 16;
        uint4 h0 = *reinterpret_cast<const uint4*>(r);
        uint4 h1 = *reinterpret_cast<const uint4*>(r + 8);
        ag[0] += bflo(h0.x); ag[1] += bfhi(h0.x); ag[2]  += bflo(h0.y); ag[3]  += bfhi(h0.y);
        ag[4] += bflo(h0.z); ag[5] += bfhi(h0.z); ag[6]  += bflo(h0.w); ag[7]  += bfhi(h0.w);
        ag[8] += bflo(h1.x); ag[9] += bfhi(h1.x); ag[10] += bflo(h1.y); ag[11] += bfhi(h1.y);
        ag[12] += bflo(h1.z); ag[13] += bfhi(h1.z); ag[14] += bflo(h1.w); ag[15] += bfhi(h1.w);
    }
#pragma unroll
    for (int m = 1; m <= 4; m <<= 1) {
#pragma unroll
        for (int j = 0; j < 16; ++j) ag[j] += __shfl_xor(ag[j], m);
    }
    if (l < 4) {
        float4 hr = *reinterpret_cast<const float4*>(hr2 + (size_t)n * 16 + l * 4);
        float4 bb = *reinterpret_cast<const float4*>(b2 + l * 4);
        float v0 = hr.x + bb.x + ag[l * 4 + 0] * iv;
        float v1 = hr.y + bb.y + ag[l * 4 + 1] * iv;
        float v2 = hr.z + bb.z + ag[l * 4 + 2] * iv;
        float v3 = hr.w + bb.w + ag[l * 4 + 3] * iv;
        float m4 = fmaxf(fmaxf(v0, v1), fmaxf(v2, v3));
        m4 = fmaxf(m4, __shfl_xor(m4, 1));
        m4 = fmaxf(m4, __shfl_xor(m4, 2));
        float s4 = expf(v0 - m4) + expf(v1 - m4) + expf(v2 - m4) + expf(v3 - m4);
        s4 += __shfl_xor(s4, 1);
        s4 += __shfl_xor(s4, 2);
        float lse = m4 + logf(s4);
        *reinterpret_cast<float4*>(out + (size_t)n * 16 + l * 4) =
            make_float4(v0 - lse, v1 - lse, v2 - lse, v3 - lse);
    }
}

// ---------------- host launcher ----------------

extern "C" void kernel_launch(void* const* d_in, const int* in_sizes, int n_in,
                              void* d_out, int out_size, void* d_ws, size_t ws_size,
                              hipStream_t stream) {
    const float* x   = (const float*)d_in[0];
    const int*   ei  = (const int*)d_in[1];
    const float* Wl0 = (const float*)d_in[2];
    const float* bl0 = (const float*)d_in[3];
    const float* Wr0 = (const float*)d_in[4];
    const float* Wl1 = (const float*)d_in[5];
    const float* bl1 = (const float*)d_in[6];
    const float* Wr1 = (const float*)d_in[7];
    const float* Wl2 = (const float*)d_in[8];
    const float* bl2 = (const float*)d_in[9];
    const float* Wr2 = (const float*)d_in[10];
    float* out = (float*)d_out;

    const int* e_src = ei;       // edge_index[0]
    const int* e_dst = ei + NE;  // edge_index[1]

    // workspace carve-out (256B aligned)
    char* ws = (char*)d_ws;
    size_t off = 0;
    auto carve = [&](size_t bytes) -> void* {
        void* p = ws + off;
        off = (off + bytes + 255) & ~(size_t)255;
        return p;
    };
    int*   deg  = (int*)carve((size_t)(NN + 128) * 4);  // deg | hist(32) | cursor(32) | done(1)
    int*   hist = deg + NN;
    int*   curs = deg + NN + 32;
    int*   done = deg + NN + 64;
    int*   cur  = (int*)carve((size_t)NN * 4);
    int*   bsum = (int*)carve(512 * 4);
    int*   col2 = (int*)carve((size_t)(NE + 3 * NN + 64) * 4);  // padded CSR
    int4*  desc = (int4*)carve((size_t)NN * 16);
    u16*   xb   = (u16*)carve((size_t)(NN + 1) * DD * 2);       // +1: zero row
    u16*   H1   = (u16*)carve((size_t)(NN + 1) * DD * 2);       // +1: zero row
    u16*   Wc0  = (u16*)carve((size_t)128 * 256 * 2);
    u16*   Wc1  = (u16*)carve((size_t)128 * 256 * 2);
    u16*   Wc2  = (u16*)carve((size_t)32 * 128 * 2);
    u16*   hl2b = (u16*)carve((size_t)(NN + 1) * 16 * 2);       // +1: zero row
    float* hr2  = (float*)carve((size_t)NN * 16 * 4);
    (void)ws_size; (void)in_sizes; (void)n_in; (void)out_size;

    // setup: zero {deg|hist|cursor|done}, then sectioned prep
    hipMemsetAsync(deg, 0, (size_t)(NN + 128) * 4, stream);
    k_setup<<<NB_CAST + NB_PREPW + NB_PREPW2 + NB_DEG + 1, 256, 0, stream>>>(
        x, xb, Wl0, Wr0, Wl1, Wr1, Wl2, Wr2, Wc0, Wc1, Wc2, e_dst, deg, H1, hl2b);

    // padded CSR + descriptor (degree-bucketed, heavy-first)
    k_scan1<<<NB_SCAN, 256, 0, stream>>>(deg, bsum, hist, done, curs);   // + merged scan2
    k_scan3<<<NB_SCAN, 256, 0, stream>>>(deg, bsum, cur, col2, curs, desc);
    k_scatter<<<(NE / 2 + 255) / 256, 256, 0, stream>>>(e_src, e_dst, cur, col2);

    // layer 0: H1 = relu([gather(xb)|xb]@Wc0 + bl0)
    k_fused_layer<true, false><<<NN / 32, 256, 0, stream>>>(
        xb, col2, desc, Wc0, bl0, H1, nullptr, nullptr, nullptr);

    // layer 1 + fused layer-2 transforms (H2 stays in LDS; hl2b/hr2 out)
    k_fused_layer<false, true><<<NN / 32, 256, 0, stream>>>(
        H1, col2, desc, Wc1, bl1, nullptr, Wc2, hl2b, hr2);

    // layer 2 final: fused mean-gather + log_softmax
    k_l2_final<<<NN / 32, 256, 0, stream>>>(hl2b, hr2, col2, desc, bl2, out);
}

// Round 13
// 196.168 us; speedup vs baseline: 1.0489x; 1.0489x over previous
//
#include <hip/hip_runtime.h>
#include <math.h>

#define NN 100000   // nodes
#define NE 600000   // edges
#define DD 128      // hidden dim
#define NB_SCAN 98  // ceil(NN/1024)

// k_setup grid sections
#define NB_CAST 12500   // NN*32 float4s / 256
#define NB_PREPW 64     // 128*128 / 256
#define NB_PREPW2 8     // 16*128 / 256
#define NB_DEG 2344     // ceil(NE/256)

typedef __attribute__((ext_vector_type(8))) short bf16x8;
typedef __attribute__((ext_vector_type(4))) float f32x4;
typedef __attribute__((ext_vector_type(4))) unsigned int u32x4;  // clang vector for NT stores
typedef unsigned short u16;
typedef unsigned int u32;

__device__ __forceinline__ float bflo(u32 w) {
    union { u32 i; float f; } v; v.i = w << 16; return v.f;
}
__device__ __forceinline__ float bfhi(u32 w) {
    union { u32 i; float f; } v; v.i = w & 0xffff0000u; return v.f;
}
__device__ __forceinline__ u16 f2bf(float f) {
    union { float f; u32 u; } v; v.f = f;
    u32 r = v.u + 0x7fffu + ((v.u >> 16) & 1u);  // RNE
    return (u16)(r >> 16);
}

// ---------------- setup: cast + weight prep + degree + zero-rows ----------

__global__ __launch_bounds__(256) void k_setup(const float* __restrict__ x,
                                               u16* __restrict__ xb,
                                               const float* __restrict__ Wl0,
                                               const float* __restrict__ Wr0,
                                               const float* __restrict__ Wl1,
                                               const float* __restrict__ Wr1,
                                               const float* __restrict__ Wl2,
                                               const float* __restrict__ Wr2,
                                               u16* __restrict__ Wc0,
                                               u16* __restrict__ Wc1,
                                               u16* __restrict__ Wc2,
                                               const int* __restrict__ dst,
                                               int* __restrict__ deg,
                                               u16* __restrict__ H1,
                                               u16* __restrict__ hl2b) {
    int b = blockIdx.x;
    int tid = threadIdx.x;
    if (b < NB_CAST) {
        int i = b * 256 + tid;               // float4 index, exact
        float4 v = reinterpret_cast<const float4*>(x)[i];
        ushort4 o;
        o.x = f2bf(v.x); o.y = f2bf(v.y); o.z = f2bf(v.z); o.w = f2bf(v.w);
        reinterpret_cast<ushort4*>(xb)[i] = o;
    } else if (b < NB_CAST + NB_PREPW) {
        int t = (b - NB_CAST) * 256 + tid;   // 0..16383, exact
        int j = t >> 7, k = t & 127;
        Wc0[j * 256 + k]       = f2bf(Wl0[t]);
        Wc0[j * 256 + 128 + k] = f2bf(Wr0[t]);
        Wc1[j * 256 + k]       = f2bf(Wl1[t]);
        Wc1[j * 256 + 128 + k] = f2bf(Wr1[t]);
    } else if (b < NB_CAST + NB_PREPW + NB_PREPW2) {
        int t = (b - NB_CAST - NB_PREPW) * 256 + tid;  // 0..2047
        int j = t >> 7, k = t & 127;
        Wc2[j * 128 + k]        = f2bf(Wl2[t]);
        Wc2[(16 + j) * 128 + k] = f2bf(Wr2[t]);
    } else if (b < NB_CAST + NB_PREPW + NB_PREPW2 + NB_DEG) {
        int e = (b - NB_CAST - NB_PREPW - NB_PREPW2) * 256 + tid;
        if (e < NE) atomicAdd(&deg[dst[e]], 1);
    } else {
        // zero rows at index NN (targets of padded edges)
        if (tid < DD) { xb[(size_t)NN * DD + tid] = 0; H1[(size_t)NN * DD + tid] = 0; }
        if (tid < 16) hl2b[(size_t)NN * 16 + tid] = 0;
    }
}

// ---------------- CSR build (padded to multiples of 4) ----------------

__global__ __launch_bounds__(256) void k_scan1(const int* __restrict__ deg,
                                               int* __restrict__ bsum,
                                               int* __restrict__ hist) {
    __shared__ int sm[256];
    __shared__ int lh[32];
    int t = threadIdx.x;
    if (t < 32) lh[t] = 0;
    int idx = blockIdx.x * 1024 + t * 4;
    int4 v = make_int4(0, 0, 0, 0);
    if (idx + 3 < NN) v = *reinterpret_cast<const int4*>(deg + idx);
    else {
        if (idx     < NN) v.x = deg[idx];
        if (idx + 1 < NN) v.y = deg[idx + 1];
        if (idx + 2 < NN) v.z = deg[idx + 2];
        if (idx + 3 < NN) v.w = deg[idx + 3];
    }
    int p0 = (v.x + 3) & ~3, p1 = (v.y + 3) & ~3, p2 = (v.z + 3) & ~3, p3 = (v.w + 3) & ~3;
    sm[t] = p0 + p1 + p2 + p3;
    __syncthreads();
    if (idx     < NN) atomicAdd(&lh[min(p0 >> 2, 31)], 1);
    if (idx + 1 < NN) atomicAdd(&lh[min(p1 >> 2, 31)], 1);
    if (idx + 2 < NN) atomicAdd(&lh[min(p2 >> 2, 31)], 1);
    if (idx + 3 < NN) atomicAdd(&lh[min(p3 >> 2, 31)], 1);
    __syncthreads();
    if (t < 32) atomicAdd(&hist[t], lh[t]);
    for (int off = 128; off > 0; off >>= 1) {
        if (t < off) sm[t] += sm[t + off];
        __syncthreads();
    }
    if (t == 0) bsum[blockIdx.x] = sm[0];
}

__global__ __launch_bounds__(128) void k_scan2(int* __restrict__ bsum,
                                               const int* __restrict__ hist,
                                               int* __restrict__ cursor) {
    __shared__ int sm[128];
    int t = threadIdx.x;
    int v = (t < NB_SCAN) ? bsum[t] : 0;
    sm[t] = v;
    __syncthreads();
    for (int off = 1; off < 128; off <<= 1) {
        int add = (t >= off) ? sm[t - off] : 0;
        __syncthreads();
        sm[t] += add;
        __syncthreads();
    }
    if (t < NB_SCAN) bsum[t] = (t == 0) ? 0 : sm[t - 1];  // exclusive, in-place
    if (t == 0) {   // DESCENDING bucket order: heavy blocks dispatched first
        int r = 0;
        for (int c = 31; c >= 0; --c) { cursor[c] = r; r += hist[c]; }
    }
}

// scan3: padded CSR offsets + pad-fill + per-node descriptor (bucketed order)
__global__ __launch_bounds__(256) void k_scan3(const int* __restrict__ deg,
                                               const int* __restrict__ boff,
                                               int* __restrict__ cur,
                                               int* __restrict__ col2,
                                               int* __restrict__ cursor,
                                               int4* __restrict__ desc) {
    __shared__ int sm[256];
    __shared__ int lh[32];
    __shared__ int lb[32];
    int t = threadIdx.x;
    if (t < 32) lh[t] = 0;
    int idx = blockIdx.x * 1024 + t * 4;
    int4 v = make_int4(0, 0, 0, 0);
    if (idx + 3 < NN) v = *reinterpret_cast<const int4*>(deg + idx);
    else {
        if (idx     < NN) v.x = deg[idx];
        if (idx + 1 < NN) v.y = deg[idx + 1];
        if (idx + 2 < NN) v.z = deg[idx + 2];
        if (idx + 3 < NN) v.w = deg[idx + 3];
    }
    int p0 = (v.x + 3) & ~3, p1 = (v.y + 3) & ~3, p2 = (v.z + 3) & ~3, p3 = (v.w + 3) & ~3;
    sm[t] = p0 + p1 + p2 + p3;
    __syncthreads();
    for (int off = 1; off < 256; off <<= 1) {
        int add = (t >= off) ? sm[t - off] : 0;
        __syncthreads();
        sm[t] += add;
        __syncthreads();
    }
    int run = boff[blockIdx.x] + ((t == 0) ? 0 : sm[t - 1]);
    int d[4] = {v.x, v.y, v.z, v.w};
    int p[4] = {p0, p1, p2, p3};
    int begs[4], ci[4], myi[4];
#pragma unroll
    for (int i = 0; i < 4; ++i) {
        if (idx + i < NN) {
            begs[i] = run;
            cur[idx + i] = run;
            for (int q = run + d[i]; q < run + p[i]; ++q) col2[q] = NN;  // pads -> zero row
            ci[i] = min(p[i] >> 2, 31);
            myi[i] = atomicAdd(&lh[ci[i]], 1);
            run += p[i];
        }
    }
    __syncthreads();
    if (t < 32 && lh[t] > 0) lb[t] = atomicAdd(&cursor[t], lh[t]);
    __syncthreads();
#pragma unroll
    for (int i = 0; i < 4; ++i) {
        if (idx + i < NN) {
            float iv = 1.0f / (float)(d[i] > 0 ? d[i] : 1);
            desc[lb[ci[i]] + myi[i]] =
                make_int4(idx + i, begs[i], begs[i] + p[i], __float_as_int(iv));
        }
    }
}

__global__ __launch_bounds__(256) void k_scatter(const int* __restrict__ src,
                                                 const int* __restrict__ dst,
                                                 int* __restrict__ cur,
                                                 int* __restrict__ col2) {
    int e = blockIdx.x * 256 + threadIdx.x;
    if (e < NE) {
        int p = atomicAdd(&cur[dst[e]], 1);
        col2[p] = src[e];
    }
}

// ---------------- fused SAGE layer (layers 0/1) ----------------
// One block = 32 nodes via desc (degree-bucketed, heavy-first), 8 lanes/node.
// Phase 1: mean-gather with col-index prefetch pipeline -> LDS [agg|x] K=256
// swizzled (rows 512B). Phase 2: 4 waves x {2 node-groups x 32 cols}: W-frag
// register reuse x2, 32 MFMAs. Epilogue -> LDS -> full-row NT stores (STORE)
// or fused W2 transform producing hl2b/hr2 (DOW2; H2 never hits HBM).

template<bool STORE, bool DOW2>
__global__ __launch_bounds__(256) void k_fused_layer(const u16* __restrict__ X,
                                                     const int* __restrict__ col2,
                                                     const int4* __restrict__ desc,
                                                     const u16* __restrict__ Wc,
                                                     const float* __restrict__ b,
                                                     u16* __restrict__ out,
                                                     const u16* __restrict__ Wc2,
                                                     u16* __restrict__ hl2b,
                                                     float* __restrict__ hr2) {
    __shared__ u16 XK[32 * 256];  // 16 KB; row = local node (512 B), swizzle: byte ^ (r&7)<<4
    char* lds = reinterpret_cast<char*>(XK);

    int tid = threadIdx.x;
    int nl = tid >> 3;     // local node 0..31
    int sl = tid & 7;      // 32B k-slice 0..7
    int4 d = desc[blockIdx.x * 32 + nl];
    int n = d.x, beg = d.y, end = d.z;
    float iv = __int_as_float(d.w);
    int m = (nl & 7) << 4;

    // first col quad as early as possible (starts the pointer chain)
    int4 c = make_int4(NN, NN, NN, NN);
    if (beg < end) c = *reinterpret_cast<const int4*>(col2 + beg);

    // self row -> LDS bytes [256 + sl*32, +32)
    {
        const u16* xs = X + (size_t)n * DD + sl * 16;
        uint4 s0 = *reinterpret_cast<const uint4*>(xs);
        uint4 s1 = *reinterpret_cast<const uint4*>(xs + 8);
        int boff = 256 + sl * 32;
        *reinterpret_cast<uint4*>(lds + nl * 512 + (boff ^ m)) = s0;
        *reinterpret_cast<uint4*>(lds + nl * 512 + ((boff + 16) ^ m)) = s1;
    }

    // mean-gather: padded list (multiple of 4), col prefetch pipeline
    float a0 = 0.f, a1 = 0.f, a2 = 0.f, a3 = 0.f, a4 = 0.f, a5 = 0.f, a6 = 0.f, a7 = 0.f;
    float a8 = 0.f, a9 = 0.f, a10 = 0.f, a11 = 0.f, a12 = 0.f, a13 = 0.f, a14 = 0.f, a15 = 0.f;
    for (int e = beg; e < end; e += 4) {
        int4 cn = make_int4(NN, NN, NN, NN);
        if (e + 4 < end) cn = *reinterpret_cast<const int4*>(col2 + e + 4);
        const u16* p0 = X + (size_t)c.x * DD + sl * 16;
        const u16* p1 = X + (size_t)c.y * DD + sl * 16;
        const u16* p2 = X + (size_t)c.z * DD + sl * 16;
        const u16* p3 = X + (size_t)c.w * DD + sl * 16;
        uint4 v0 = *reinterpret_cast<const uint4*>(p0);
        uint4 w0 = *reinterpret_cast<const uint4*>(p0 + 8);
        uint4 v1 = *reinterpret_cast<const uint4*>(p1);
        uint4 w1 = *reinterpret_cast<const uint4*>(p1 + 8);
        uint4 v2 = *reinterpret_cast<const uint4*>(p2);
        uint4 w2 = *reinterpret_cast<const uint4*>(p2 + 8);
        uint4 v3 = *reinterpret_cast<const uint4*>(p3);
        uint4 w3 = *reinterpret_cast<const uint4*>(p3 + 8);
        a0  += (bflo(v0.x) + bflo(v1.x)) + (bflo(v2.x) + bflo(v3.x));
        a1  += (bfhi(v0.x) + bfhi(v1.x)) + (bfhi(v2.x) + bfhi(v3.x));
        a2  += (bflo(v0.y) + bflo(v1.y)) + (bflo(v2.y) + bflo(v3.y));
        a3  += (bfhi(v0.y) + bfhi(v1.y)) + (bfhi(v2.y) + bfhi(v3.y));
        a4  += (bflo(v0.z) + bflo(v1.z)) + (bflo(v2.z) + bflo(v3.z));
        a5  += (bfhi(v0.z) + bfhi(v1.z)) + (bfhi(v2.z) + bfhi(v3.z));
        a6  += (bflo(v0.w) + bflo(v1.w)) + (bflo(v2.w) + bflo(v3.w));
        a7  += (bfhi(v0.w) + bfhi(v1.w)) + (bfhi(v2.w) + bfhi(v3.w));
        a8  += (bflo(w0.x) + bflo(w1.x)) + (bflo(w2.x) + bflo(w3.x));
        a9  += (bfhi(w0.x) + bfhi(w1.x)) + (bfhi(w2.x) + bfhi(w3.x));
        a10 += (bflo(w0.y) + bflo(w1.y)) + (bflo(w2.y) + bflo(w3.y));
        a11 += (bfhi(w0.y) + bfhi(w1.y)) + (bfhi(w2.y) + bfhi(w3.y));
        a12 += (bflo(w0.z) + bflo(w1.z)) + (bflo(w2.z) + bflo(w3.z));
        a13 += (bfhi(w0.z) + bfhi(w1.z)) + (bfhi(w2.z) + bfhi(w3.z));
        a14 += (bflo(w0.w) + bflo(w1.w)) + (bflo(w2.w) + bflo(w3.w));
        a15 += (bfhi(w0.w) + bfhi(w1.w)) + (bfhi(w2.w) + bfhi(w3.w));
        c = cn;
    }
    uint4 o0, o1;
    o0.x = (u32)f2bf(a0 * iv)  | ((u32)f2bf(a1 * iv)  << 16);
    o0.y = (u32)f2bf(a2 * iv)  | ((u32)f2bf(a3 * iv)  << 16);
    o0.z = (u32)f2bf(a4 * iv)  | ((u32)f2bf(a5 * iv)  << 16);
    o0.w = (u32)f2bf(a6 * iv)  | ((u32)f2bf(a7 * iv)  << 16);
    o1.x = (u32)f2bf(a8 * iv)  | ((u32)f2bf(a9 * iv)  << 16);
    o1.y = (u32)f2bf(a10 * iv) | ((u32)f2bf(a11 * iv) << 16);
    o1.z = (u32)f2bf(a12 * iv) | ((u32)f2bf(a13 * iv) << 16);
    o1.w = (u32)f2bf(a14 * iv) | ((u32)f2bf(a15 * iv) << 16);
    *reinterpret_cast<uint4*>(lds + nl * 512 + ((sl * 32) ^ m)) = o0;
    *reinterpret_cast<uint4*>(lds + nl * 512 + ((sl * 32 + 16) ^ m)) = o1;
    __syncthreads();

    // ---- phase 2: GEMM (W-frag reused across 2 node-groups) ----
    int wid = tid >> 6, lane = tid & 63;
    int cl = lane & 15, rq = lane >> 4;
    int xm = (cl & 7) << 4;

    f32x4 acc00 = (f32x4){0.f, 0.f, 0.f, 0.f};
    f32x4 acc01 = (f32x4){0.f, 0.f, 0.f, 0.f};
    f32x4 acc10 = (f32x4){0.f, 0.f, 0.f, 0.f};
    f32x4 acc11 = (f32x4){0.f, 0.f, 0.f, 0.f};
    const u16* wbase = Wc + (size_t)(wid * 32 + cl) * 256 + rq * 8;
    const char* x0b = lds + cl * 512;
    const char* x1b = lds + (16 + cl) * 512;
#pragma unroll
    for (int ks = 0; ks < 8; ++ks) {
        int xo = (ks * 64 + rq * 16) ^ xm;
        bf16x8 xf0 = *reinterpret_cast<const bf16x8*>(x0b + xo);
        bf16x8 xf1 = *reinterpret_cast<const bf16x8*>(x1b + xo);
        bf16x8 wf0 = *reinterpret_cast<const bf16x8*>(wbase + ks * 32);
        bf16x8 wf1 = *reinterpret_cast<const bf16x8*>(wbase + 16 * 256 + ks * 32);
        acc00 = __builtin_amdgcn_mfma_f32_16x16x32_bf16(wf0, xf0, acc00, 0, 0, 0);
        acc01 = __builtin_amdgcn_mfma_f32_16x16x32_bf16(wf1, xf0, acc01, 0, 0, 0);
        acc10 = __builtin_amdgcn_mfma_f32_16x16x32_bf16(wf0, xf1, acc10, 0, 0, 0);
        acc11 = __builtin_amdgcn_mfma_f32_16x16x32_bf16(wf1, xf1, acc11, 0, 0, 0);
    }
    __syncthreads();   // XK reads done; safe to overwrite with output tile

    // bias + relu + pack -> LDS (node-row g*16+cl, col bytes (j*2)^swz)
#pragma unroll
    for (int g = 0; g < 2; ++g) {
#pragma unroll
        for (int jf = 0; jf < 2; ++jf) {
            f32x4 a = g ? (jf ? acc11 : acc10) : (jf ? acc01 : acc00);
            int j0 = wid * 32 + jf * 16 + rq * 4;
            float4 bias = *reinterpret_cast<const float4*>(b + j0);
            float o0f = fmaxf(a[0] + bias.x, 0.f);
            float o1f = fmaxf(a[1] + bias.y, 0.f);
            float o2f = fmaxf(a[2] + bias.z, 0.f);
            float o3f = fmaxf(a[3] + bias.w, 0.f);
            uint2 pk;
            pk.x = (u32)f2bf(o0f) | ((u32)f2bf(o1f) << 16);
            pk.y = (u32)f2bf(o2f) | ((u32)f2bf(o3f) << 16);
            int row = g * 16 + cl;
            *reinterpret_cast<uint2*>(lds + row * 512 + ((j0 * 2) ^ ((cl & 7) << 4))) = pk;
        }
    }
    __syncthreads();

    if (STORE) {
        // full-row NT stores (don't evict the gather table from L2):
        // thread (nl, sl) stores bytes [sl*32, +32) of row n
        u32x4 q0 = *reinterpret_cast<const u32x4*>(lds + nl * 512 + ((sl * 32) ^ m));
        u32x4 q1 = *reinterpret_cast<const u32x4*>(lds + nl * 512 + ((sl * 32 + 16) ^ m));
        u32x4* orow = reinterpret_cast<u32x4*>(out + (size_t)n * DD + sl * 16);
        __builtin_nontemporal_store(q0, orow);
        __builtin_nontemporal_store(q1, orow + 1);
    }

    if (DOW2) {
        // fused layer-2 transforms from the LDS output tile (K=128)
        int g = wid >> 1, tbl = wid & 1;
        f32x4 a2 = (f32x4){0.f, 0.f, 0.f, 0.f};
        const u16* wb = Wc2 + (size_t)(tbl * 16 + cl) * 128 + rq * 8;
        const char* xb = lds + (size_t)(g * 16 + cl) * 512;
#pragma unroll
        for (int ks = 0; ks < 4; ++ks) {
            bf16x8 xf = *reinterpret_cast<const bf16x8*>(xb + ((ks * 64 + rq * 16) ^ xm));
            bf16x8 wf = *reinterpret_cast<const bf16x8*>(wb + ks * 32);
            a2 = __builtin_amdgcn_mfma_f32_16x16x32_bf16(wf, xf, a2, 0, 0, 0);
        }
        int n2 = desc[blockIdx.x * 32 + g * 16 + cl].x;
        if (tbl == 0) {
            uint2 pk;
            pk.x = (u32)f2bf(a2[0]) | ((u32)f2bf(a2[1]) << 16);
            pk.y = (u32)f2bf(a2[2]) | ((u32)f2bf(a2[3]) << 16);
            *reinterpret_cast<uint2*>(hl2b + (size_t)n2 * 16 + rq * 4) = pk;
        } else {
            *reinterpret_cast<float4*>(hr2 + (size_t)n2 * 16 + rq * 4) =
                make_float4(a2[0], a2[1], a2[2], a2[3]);
        }
    }
}

// ---------------- layer 2 final ----------------

// k_l2_final: 8 lanes/node mean-gather(hl2b) + hr2 + bias -> log_softmax.
__global__ __launch_bounds__(256) void k_l2_final(const u16* __restrict__ hl2b,
                                                  const float* __restrict__ hr2,
                                                  const int* __restrict__ col2,
                                                  const int4* __restrict__ desc,
                                                  const float* __restrict__ b2,
                                                  float* __restrict__ out) {
    int tid = threadIdx.x;
    int ns = tid >> 3;   // node slot 0..31
    int l  = tid & 7;
    int4 d = desc[blockIdx.x * 32 + ns];
    int n = d.x, beg = d.y, end = d.z;
    float iv = __int_as_float(d.w);

    float ag[16];
#pragma unroll
    for (int j = 0; j < 16; ++j) ag[j] = 0.f;
    for (int e = beg + l; e < end; e += 8) {
        const u16* r = hl2b + (size_t)col2[e] * 16;
        uint4 h0 = *reinterpret_cast<const uint4*>(r);
        uint4 h1 = *reinterpret_cast<const uint4*>(r + 8);
        ag[0] += bflo(h0.x); ag[1] += bfhi(h0.x); ag[2]  += bflo(h0.y); ag[3]  += bfhi(h0.y);
        ag[4] += bflo(h0.z); ag[5] += bfhi(h0.z); ag[6]  += bflo(h0.w); ag[7]  += bfhi(h0.w);
        ag[8] += bflo(h1.x); ag[9] += bfhi(h1.x); ag[10] += bflo(h1.y); ag[11] += bfhi(h1.y);
        ag[12] += bflo(h1.z); ag[13] += bfhi(h1.z); ag[14] += bflo(h1.w); ag[15] += bfhi(h1.w);
    }
#pragma unroll
    for (int m = 1; m <= 4; m <<= 1) {
#pragma unroll
        for (int j = 0; j < 16; ++j) ag[j] += __shfl_xor(ag[j], m);
    }
    if (l < 4) {
        float4 hr = *reinterpret_cast<const float4*>(hr2 + (size_t)n * 16 + l * 4);
        float4 bb = *reinterpret_cast<const float4*>(b2 + l * 4);
        float v0 = hr.x + bb.x + ag[l * 4 + 0] * iv;
        float v1 = hr.y + bb.y + ag[l * 4 + 1] * iv;
        float v2 = hr.z + bb.z + ag[l * 4 + 2] * iv;
        float v3 = hr.w + bb.w + ag[l * 4 + 3] * iv;
        float m4 = fmaxf(fmaxf(v0, v1), fmaxf(v2, v3));
        m4 = fmaxf(m4, __shfl_xor(m4, 1));
        m4 = fmaxf(m4, __shfl_xor(m4, 2));
        float s4 = expf(v0 - m4) + expf(v1 - m4) + expf(v2 - m4) + expf(v3 - m4);
        s4 += __shfl_xor(s4, 1);
        s4 += __shfl_xor(s4, 2);
        float lse = m4 + logf(s4);
        *reinterpret_cast<float4*>(out + (size_t)n * 16 + l * 4) =
            make_float4(v0 - lse, v1 - lse, v2 - lse, v3 - lse);
    }
}

// ---------------- host launcher ----------------

extern "C" void kernel_launch(void* const* d_in, const int* in_sizes, int n_in,
                              void* d_out, int out_size, void* d_ws, size_t ws_size,
                              hipStream_t stream) {
    const float* x   = (const float*)d_in[0];
    const int*   ei  = (const int*)d_in[1];
    const float* Wl0 = (const float*)d_in[2];
    const float* bl0 = (const float*)d_in[3];
    const float* Wr0 = (const float*)d_in[4];
    const float* Wl1 = (const float*)d_in[5];
    const float* bl1 = (const float*)d_in[6];
    const float* Wr1 = (const float*)d_in[7];
    const float* Wl2 = (const float*)d_in[8];
    const float* bl2 = (const float*)d_in[9];
    const float* Wr2 = (const float*)d_in[10];
    float* out = (float*)d_out;

    const int* e_src = ei;       // edge_index[0]
    const int* e_dst = ei + NE;  // edge_index[1]

    // workspace carve-out (256B aligned)
    char* ws = (char*)d_ws;
    size_t off = 0;
    auto carve = [&](size_t bytes) -> void* {
        void* p = ws + off;
        off = (off + bytes + 255) & ~(size_t)255;
        return p;
    };
    int*   deg  = (int*)carve((size_t)(NN + 128) * 4);  // deg | hist(32) | cursor(32)
    int*   hist = deg + NN;
    int*   curs = deg + NN + 32;
    int*   cur  = (int*)carve((size_t)NN * 4);
    int*   bsum = (int*)carve(512 * 4);
    int*   col2 = (int*)carve((size_t)(NE + 3 * NN + 64) * 4);  // padded CSR
    int4*  desc = (int4*)carve((size_t)NN * 16);
    u16*   xb   = (u16*)carve((size_t)(NN + 1) * DD * 2);       // +1: zero row
    u16*   H1   = (u16*)carve((size_t)(NN + 1) * DD * 2);       // +1: zero row
    u16*   Wc0  = (u16*)carve((size_t)128 * 256 * 2);
    u16*   Wc1  = (u16*)carve((size_t)128 * 256 * 2);
    u16*   Wc2  = (u16*)carve((size_t)32 * 128 * 2);
    u16*   hl2b = (u16*)carve((size_t)(NN + 1) * 16 * 2);       // +1: zero row
    float* hr2  = (float*)carve((size_t)NN * 16 * 4);
    (void)ws_size; (void)in_sizes; (void)n_in; (void)out_size;

    // setup: zero {deg|hist|cursor}, then sectioned prep
    hipMemsetAsync(deg, 0, (size_t)(NN + 128) * 4, stream);
    k_setup<<<NB_CAST + NB_PREPW + NB_PREPW2 + NB_DEG + 1, 256, 0, stream>>>(
        x, xb, Wl0, Wr0, Wl1, Wr1, Wl2, Wr2, Wc0, Wc1, Wc2, e_dst, deg, H1, hl2b);

    // padded CSR + descriptor (degree-bucketed, heavy-first)
    k_scan1<<<NB_SCAN, 256, 0, stream>>>(deg, bsum, hist);
    k_scan2<<<1, 128, 0, stream>>>(bsum, hist, curs);
    k_scan3<<<NB_SCAN, 256, 0, stream>>>(deg, bsum, cur, col2, curs, desc);
    k_scatter<<<(NE + 255) / 256, 256, 0, stream>>>(e_src, e_dst, cur, col2);

    // layer 0: H1 = relu([gather(xb)|xb]@Wc0 + bl0)
    k_fused_layer<true, false><<<NN / 32, 256, 0, stream>>>(
        xb, col2, desc, Wc0, bl0, H1, nullptr, nullptr, nullptr);

    // layer 1 + fused layer-2 transforms (H2 stays in LDS; hl2b/hr2 out)
    k_fused_layer<false, true><<<NN / 32, 256, 0, stream>>>(
        H1, col2, desc, Wc1, bl1, nullptr, Wc2, hl2b, hr2);

    // layer 2 final: fused mean-gather + log_softmax
    k_l2_final<<<NN / 32, 256, 0, stream>>>(hl2b, hr2, col2, desc, bl2, out);
}